// Round 1
// baseline (530.521 us; speedup 1.0000x reference)
//
#include <hip/hip_runtime.h>
#include <hip/hip_bf16.h>

#define B_ 128
#define L_ 4096
#define D_ 128
#define E_ 64

typedef __attribute__((ext_vector_type(8))) short short8;
typedef __attribute__((ext_vector_type(4))) float floatx4;

static __device__ __forceinline__ unsigned short f2bf(float x) {
  __hip_bfloat16 h = __float2bfloat16(x);
  union { __hip_bfloat16 h; unsigned short u; } c; c.h = h; return c.u;
}
static __device__ __forceinline__ float bf2f(unsigned short u) {
  union { unsigned short u; __hip_bfloat16 h; } c; c.u = u; return __bfloat162float(c.h);
}

// ---------------- pass A: c[b][d] = bias_r[d] + sum_e q[b][e]*Wr2[d][e],
//                  q[b][e] = sum_d' target[b][d']*Wf_w[e][d'] + Wf_b[e]
__global__ __launch_bounds__(128) void pass_a(
    const float* __restrict__ target, const float* __restrict__ Wr2,
    const float* __restrict__ bias_r, const float* __restrict__ Wf_w,
    const float* __restrict__ Wf_b, float* __restrict__ cvec) {
  const int b = blockIdx.x, t = threadIdx.x;
  __shared__ float tg[D_];
  __shared__ float q[E_];
  tg[t] = target[b * D_ + t];
  __syncthreads();
  if (t < E_) {
    float s = Wf_b[t];
    #pragma unroll 8
    for (int d = 0; d < D_; ++d) s += tg[d] * Wf_w[t * D_ + d];
    q[t] = s;
  }
  __syncthreads();
  float s = bias_r[t];
  #pragma unroll 8
  for (int e = 0; e < E_; ++e) s += q[e] * Wr2[t * E_ + e];
  cvec[b * D_ + t] = s;
}

// ---------------- split + fragment-swizzle Wr1 (B operand: B[k=d][n=e] = Wr1[e][d])
// dst layout: [nt(8)][ks(4)][lane(64)][j(8)]
__global__ __launch_bounds__(256) void wr1_split(const float* __restrict__ Wr1,
    unsigned short* __restrict__ hi, unsigned short* __restrict__ lo) {
  int t = blockIdx.x * 256 + threadIdx.x;  // 0..16383
  int j = t & 7, lane = (t >> 3) & 63, ks = (t >> 9) & 3, nt = t >> 11;
  int e = nt * 16 + (lane & 15);
  int d = ks * 32 + (lane >> 4) * 8 + j;
  float x = Wr1[e * D_ + d];
  unsigned short h = f2bf(x);
  hi[t] = h;
  lo[t] = f2bf(x - bf2f(h));
}

// ---------------- pass B: scores[b][l] = sum_e Wr3[e]*relu( R[b][l]·Wr1[e] + c[b][e] )
// split-bf16 MFMA GEMM, BM=128 rows/block, 4 waves, each wave owns 2 n-tiles.
__global__ __launch_bounds__(256, 2) void pass_b(
    const float* __restrict__ R, const unsigned short* __restrict__ Whi,
    const unsigned short* __restrict__ Wlo, const float* __restrict__ cvec,
    const float* __restrict__ Wr3, float* __restrict__ scores) {
  __shared__ __align__(16) unsigned short sAhi[16384];  // 32 KB, frag-swizzled
  __shared__ __align__(16) unsigned short sAlo[16384];  // 32 KB
  const int b = blockIdx.x >> 5;
  const int lt = blockIdx.x & 31;
  const int t = threadIdx.x;
  const int wave = t >> 6, lane = t & 63;
  const int col = lane & 15, quad = lane >> 4;

  // stage A tile: 128x128 fp32 -> hi/lo bf16 in MFMA fragment order
  const float* Rbase = R + ((size_t)b * L_ + (size_t)lt * 128) * D_;
  const float4* R4 = (const float4*)Rbase;
  #pragma unroll
  for (int it = 0; it < 16; ++it) {
    int f = it * 256 + t;
    int row = f >> 5, c4 = f & 31;
    float4 v = R4[f];
    int d = c4 * 4;
    int mt = row >> 4, lb = row & 15;
    int ks = d >> 5, qd = (d >> 3) & 3, j0 = d & 7;
    int base = ((mt * 4 + ks) * 64 + (qd * 16 + lb)) * 8 + j0;
    ushort4 h, l;
    h.x = f2bf(v.x); l.x = f2bf(v.x - bf2f(h.x));
    h.y = f2bf(v.y); l.y = f2bf(v.y - bf2f(h.y));
    h.z = f2bf(v.z); l.z = f2bf(v.z - bf2f(h.z));
    h.w = f2bf(v.w); l.w = f2bf(v.w - bf2f(h.w));
    *(ushort4*)(sAhi + base) = h;
    *(ushort4*)(sAlo + base) = l;
  }

  // preload this wave's B fragments (2 n-tiles x 4 k-steps, hi+lo) into registers
  short8 bh[2][4], bl[2][4];
  #pragma unroll
  for (int n = 0; n < 2; ++n)
    #pragma unroll
    for (int ks = 0; ks < 4; ++ks) {
      int off = (((wave * 2 + n) * 4 + ks) * 64 + lane) * 8;
      bh[n][ks] = *(const short8*)(Whi + off);
      bl[n][ks] = *(const short8*)(Wlo + off);
    }

  floatx4 acc[8][2];
  #pragma unroll
  for (int mt = 0; mt < 8; ++mt)
    #pragma unroll
    for (int n = 0; n < 2; ++n) acc[mt][n] = (floatx4){0.f, 0.f, 0.f, 0.f};

  __syncthreads();

  #pragma unroll
  for (int mt = 0; mt < 8; ++mt) {
    #pragma unroll
    for (int ks = 0; ks < 4; ++ks) {
      int ai = ((mt * 4 + ks) * 64 + lane) * 8;
      short8 ah = *(const short8*)(sAhi + ai);
      short8 al = *(const short8*)(sAlo + ai);
      #pragma unroll
      for (int n = 0; n < 2; ++n) {
        acc[mt][n] = __builtin_amdgcn_mfma_f32_16x16x32_bf16(ah, bh[n][ks], acc[mt][n], 0, 0, 0);
        acc[mt][n] = __builtin_amdgcn_mfma_f32_16x16x32_bf16(al, bh[n][ks], acc[mt][n], 0, 0, 0);
        acc[mt][n] = __builtin_amdgcn_mfma_f32_16x16x32_bf16(ah, bl[n][ks], acc[mt][n], 0, 0, 0);
      }
    }
  }

  // epilogue: score[m] = sum_e Wr3[e]*relu(C[m][e] + c[b][e])
  float w3[2], cb[2];
  #pragma unroll
  for (int n = 0; n < 2; ++n) {
    int e = (wave * 2 + n) * 16 + col;
    w3[n] = Wr3[e];
    cb[n] = cvec[b * D_ + e];
  }
  float part[8][4];
  #pragma unroll
  for (int mt = 0; mt < 8; ++mt)
    #pragma unroll
    for (int r = 0; r < 4; ++r) {
      float s = 0.f;
      #pragma unroll
      for (int n = 0; n < 2; ++n)
        s += w3[n] * fmaxf(acc[mt][n][r] + cb[n], 0.f);
      // reduce across the 16 cols held by this quad
      s += __shfl_xor(s, 1, 64);
      s += __shfl_xor(s, 2, 64);
      s += __shfl_xor(s, 4, 64);
      s += __shfl_xor(s, 8, 64);
      part[mt][r] = s;
    }
  __syncthreads();              // A tile no longer needed; reuse as reduction buf
  float* red = (float*)sAhi;    // [4 waves][128 rows]
  if (col == 0) {
    #pragma unroll
    for (int mt = 0; mt < 8; ++mt)
      #pragma unroll
      for (int r = 0; r < 4; ++r)
        red[wave * 128 + mt * 16 + quad * 4 + r] = part[mt][r];
  }
  __syncthreads();
  if (t < 128) {
    float s = (red[t] + red[128 + t]) + (red[256 + t] + red[384 + t]);
    scores[(size_t)b * L_ + lt * 128 + t] = s;
  }
}

// ---------------- pass C: entmax bisection per batch row; compact nonzeros
__global__ __launch_bounds__(256) void pass_c(
    const float* __restrict__ scores, const float* __restrict__ alpha,
    int* __restrict__ cnt, int* __restrict__ idxs, float* __restrict__ wts) {
  const int b = blockIdx.x, t = threadIdx.x;
  const int wave = t >> 6, lane = t & 63;
  __shared__ float sred[4];
  __shared__ int scnt;
  const float am1 = alpha[b] - 1.0f;
  const float inv = 1.0f / am1;
  const float* S = scores + (size_t)b * L_;
  float Xs[16];
  #pragma unroll
  for (int i = 0; i < 16; ++i) Xs[i] = S[i * 256 + t] * am1;

  // block max
  float mx = Xs[0];
  #pragma unroll
  for (int i = 1; i < 16; ++i) mx = fmaxf(mx, Xs[i]);
  #pragma unroll
  for (int m = 32; m >= 1; m >>= 1) mx = fmaxf(mx, __shfl_xor(mx, m, 64));
  if (lane == 0) sred[wave] = mx;
  __syncthreads();
  mx = fmaxf(fmaxf(sred[0], sred[1]), fmaxf(sred[2], sred[3]));
  __syncthreads();

  float tau_lo = mx - 1.0f;
  float tau_hi = mx - exp2f(-12.0f * am1);  // (1/4096)^am1
  float dm = tau_hi - tau_lo;

  auto sumP = [&](float tau) -> float {
    float s = 0.f;
    #pragma unroll
    for (int i = 0; i < 16; ++i) {
      float u = Xs[i] - tau;
      if (u > 0.f) s += exp2f(inv * __log2f(u));
    }
    #pragma unroll
    for (int m = 32; m >= 1; m >>= 1) s += __shfl_xor(s, m, 64);
    if (lane == 0) sred[wave] = s;
    __syncthreads();
    float r = (sred[0] + sred[1]) + (sred[2] + sred[3]);
    __syncthreads();
    return r;
  };

  const float f_lo = sumP(tau_lo) - 1.0f;
  float tau_m = tau_lo;
  for (int it = 0; it < 50; ++it) {
    dm *= 0.5f;
    tau_m = tau_lo + dm;
    float f_m = sumP(tau_m) - 1.0f;
    if (f_m * f_lo >= 0.f) tau_lo = tau_m;  // uniform branch
  }

  // final p, normalize, compact nonzeros
  float p[16];
  float s = 0.f;
  #pragma unroll
  for (int i = 0; i < 16; ++i) {
    float u = Xs[i] - tau_m;
    p[i] = (u > 0.f) ? exp2f(inv * __log2f(u)) : 0.f;
    s += p[i];
  }
  #pragma unroll
  for (int m = 32; m >= 1; m >>= 1) s += __shfl_xor(s, m, 64);
  if (lane == 0) sred[wave] = s;
  if (t == 0) scnt = 0;
  __syncthreads();
  s = (sred[0] + sred[1]) + (sred[2] + sred[3]);
  const float rs = 1.0f / s;
  #pragma unroll
  for (int i = 0; i < 16; ++i) {
    if (p[i] > 0.f) {
      int pos = atomicAdd(&scnt, 1);
      idxs[b * L_ + pos] = i * 256 + t;
      wts[b * L_ + pos] = p[i] * rs;
    }
  }
  __syncthreads();
  if (t == 0) cnt[b] = scnt;
}

// ---------------- pass D: res[b][d] = normalize(selu(sum_k w_k * R[b][idx_k][d]))
__global__ __launch_bounds__(128) void pass_d(
    const float* __restrict__ R, const int* __restrict__ cnt,
    const int* __restrict__ idxs, const float* __restrict__ wts,
    float* __restrict__ out) {
  const int b = blockIdx.x, t = threadIdx.x;
  const int n = cnt[b];
  const int* id = idxs + (size_t)b * L_;
  const float* w = wts + (size_t)b * L_;
  const float* Rb = R + (size_t)b * L_ * D_;
  float acc = 0.f;
  int k = 0;
  for (; k + 4 <= n; k += 4) {
    int i0 = id[k], i1 = id[k + 1], i2 = id[k + 2], i3 = id[k + 3];
    float w0 = w[k], w1 = w[k + 1], w2 = w[k + 2], w3 = w[k + 3];
    float r0 = Rb[(size_t)i0 * D_ + t];
    float r1 = Rb[(size_t)i1 * D_ + t];
    float r2 = Rb[(size_t)i2 * D_ + t];
    float r3 = Rb[(size_t)i3 * D_ + t];
    acc += w0 * r0 + w1 * r1 + w2 * r2 + w3 * r3;
  }
  for (; k < n; ++k) acc += w[k] * Rb[(size_t)id[k] * D_ + t];
  const float sc = 1.0507009873554805f, al = 1.6732632423543772f;
  float r = acc > 0.f ? sc * acc : sc * al * (expf(acc) - 1.0f);
  __shared__ float nred[2];
  float q = r * r;
  #pragma unroll
  for (int m = 32; m >= 1; m >>= 1) q += __shfl_xor(q, m, 64);
  if ((t & 63) == 0) nred[t >> 6] = q;
  __syncthreads();
  float nrm = sqrtf(nred[0] + nred[1]);
  out[b * D_ + t] = r / nrm;
}

extern "C" void kernel_launch(void* const* d_in, const int* in_sizes, int n_in,
                              void* d_out, int out_size, void* d_ws, size_t ws_size,
                              hipStream_t stream) {
  const float* R      = (const float*)d_in[0];
  const float* alpha  = (const float*)d_in[1];
  const float* target = (const float*)d_in[2];
  const float* Wr1    = (const float*)d_in[3];
  const float* Wr2    = (const float*)d_in[4];
  const float* Wr3    = (const float*)d_in[5];
  const float* bias_r = (const float*)d_in[6];
  const float* Wf_w   = (const float*)d_in[7];
  const float* Wf_b   = (const float*)d_in[8];
  float* out = (float*)d_out;

  char* ws = (char*)d_ws;
  float* cvec          = (float*)ws;                         // 64 KB
  unsigned short* whi  = (unsigned short*)(ws + 65536);      // 32 KB
  unsigned short* wlo  = (unsigned short*)(ws + 98304);      // 32 KB
  float* scores        = (float*)(ws + 131072);              // 2 MB
  int*   idxs          = (int*)(ws + 131072 + 2097152);      // 2 MB
  float* wts           = (float*)(ws + 131072 + 2 * 2097152);// 2 MB
  int*   cnt           = (int*)(ws + 131072 + 3 * 2097152);  // 512 B

  hipLaunchKernelGGL(pass_a, dim3(B_), dim3(128), 0, stream,
                     target, Wr2, bias_r, Wf_w, Wf_b, cvec);
  hipLaunchKernelGGL(wr1_split, dim3(64), dim3(256), 0, stream, Wr1, whi, wlo);
  hipLaunchKernelGGL(pass_b, dim3(B_ * 32), dim3(256), 0, stream,
                     R, whi, wlo, cvec, Wr3, scores);
  hipLaunchKernelGGL(pass_c, dim3(B_), dim3(256), 0, stream,
                     scores, alpha, cnt, idxs, wts);
  hipLaunchKernelGGL(pass_d, dim3(B_), dim3(128), 0, stream,
                     R, cnt, idxs, wts, out);
}

// Round 2
// 458.065 us; speedup vs baseline: 1.1582x; 1.1582x over previous
//
#include <hip/hip_runtime.h>
#include <hip/hip_bf16.h>

#define B_ 128
#define L_ 4096
#define D_ 128
#define E_ 64

typedef __attribute__((ext_vector_type(8))) short short8;
typedef __attribute__((ext_vector_type(4))) float floatx4;

static __device__ __forceinline__ unsigned short f2bf(float x) {
  __hip_bfloat16 h = __float2bfloat16(x);
  union { __hip_bfloat16 h; unsigned short u; } c; c.h = h; return c.u;
}
static __device__ __forceinline__ float bf2f(unsigned short u) {
  union { unsigned short u; __hip_bfloat16 h; } c; c.u = u; return __bfloat162float(c.h);
}

// ---------------- pass A: c[b][d] = bias_r[d] + sum_e q[b][e]*Wr2[d][e],
//                  q[b][e] = sum_d' target[b][d']*Wf_w[e][d'] + Wf_b[e]
__global__ __launch_bounds__(128) void pass_a(
    const float* __restrict__ target, const float* __restrict__ Wr2,
    const float* __restrict__ bias_r, const float* __restrict__ Wf_w,
    const float* __restrict__ Wf_b, float* __restrict__ cvec) {
  const int b = blockIdx.x, t = threadIdx.x;
  __shared__ float tg[D_];
  __shared__ float q[E_];
  tg[t] = target[b * D_ + t];
  __syncthreads();
  if (t < E_) {
    float s = Wf_b[t];
    #pragma unroll 8
    for (int d = 0; d < D_; ++d) s += tg[d] * Wf_w[t * D_ + d];
    q[t] = s;
  }
  __syncthreads();
  float s = bias_r[t];
  #pragma unroll 8
  for (int e = 0; e < E_; ++e) s += q[e] * Wr2[t * E_ + e];
  cvec[b * D_ + t] = s;
}

// ---------------- split + fragment-swizzle Wr1 (B operand: B[k=d][n=e] = Wr1[e][d])
// dst layout: [nt(8)][ks(4)][lane(64)][j(8)]
__global__ __launch_bounds__(256) void wr1_split(const float* __restrict__ Wr1,
    unsigned short* __restrict__ hi, unsigned short* __restrict__ lo) {
  int t = blockIdx.x * 256 + threadIdx.x;  // 0..16383
  int j = t & 7, lane = (t >> 3) & 63, ks = (t >> 9) & 3, nt = t >> 11;
  int e = nt * 16 + (lane & 15);
  int d = ks * 32 + (lane >> 4) * 8 + j;
  float x = Wr1[e * D_ + d];
  unsigned short h = f2bf(x);
  hi[t] = h;
  lo[t] = f2bf(x - bf2f(h));
}

// ---------------- pass B: scores[b][l] = sum_e Wr3[e]*relu( R[b][l]·Wr1[e] + c[b][e] )
// split-bf16 MFMA GEMM, BM=128 rows/block, 4 waves, each wave owns 2 n-tiles.
// Staging: each lane writes ITS OWN fragment slot -> lane-contiguous 16B
// ds_write_b128, conflict-free (fragment layout is [frag][lane][8 shorts]).
__global__ __launch_bounds__(256, 2) void pass_b(
    const float* __restrict__ R, const unsigned short* __restrict__ Whi,
    const unsigned short* __restrict__ Wlo, const float* __restrict__ cvec,
    const float* __restrict__ Wr3, float* __restrict__ scores) {
  __shared__ __align__(16) unsigned short sAhi[16384];  // 32 KB, frag-swizzled
  __shared__ __align__(16) unsigned short sAlo[16384];  // 32 KB
  const int b = blockIdx.x >> 5;
  const int lt = blockIdx.x & 31;
  const int t = threadIdx.x;
  const int wave = t >> 6, lane = t & 63;
  const int col = lane & 15, quad = lane >> 4;

  const float* Rbase = R + ((size_t)b * L_ + (size_t)lt * 128) * D_;
  // wave w stages fragments (mt, ks) for mt in {2w, 2w+1}, ks 0..3.
  // lane l writes slot l: covers A[m = mt*16 + (l&15)][k = ks*32 + (l>>4)*8 + j]
  #pragma unroll
  for (int i = 0; i < 8; ++i) {
    const int mt = wave * 2 + (i >> 2);
    const int ks = i & 3;
    const int row = mt * 16 + (lane & 15);
    const int c0 = ks * 32 + (lane >> 4) * 8;
    const float4* p = (const float4*)(Rbase + (size_t)row * D_ + c0);
    float4 v0 = p[0], v1 = p[1];
    float vv[8] = {v0.x, v0.y, v0.z, v0.w, v1.x, v1.y, v1.z, v1.w};
    union { unsigned short u[8]; short8 v; } H, Lo;
    #pragma unroll
    for (int j = 0; j < 8; ++j) {
      unsigned short h = f2bf(vv[j]);
      H.u[j] = h;
      Lo.u[j] = f2bf(vv[j] - bf2f(h));
    }
    const int base = ((mt * 4 + ks) * 64 + lane) * 8;
    *(short8*)(sAhi + base) = H.v;
    *(short8*)(sAlo + base) = Lo.v;
  }

  // preload this wave's B fragments (2 n-tiles x 4 k-steps, hi+lo) into registers
  short8 bh[2][4], bl[2][4];
  #pragma unroll
  for (int n = 0; n < 2; ++n)
    #pragma unroll
    for (int ks = 0; ks < 4; ++ks) {
      int off = (((wave * 2 + n) * 4 + ks) * 64 + lane) * 8;
      bh[n][ks] = *(const short8*)(Whi + off);
      bl[n][ks] = *(const short8*)(Wlo + off);
    }

  floatx4 acc[8][2];
  #pragma unroll
  for (int mt = 0; mt < 8; ++mt)
    #pragma unroll
    for (int n = 0; n < 2; ++n) acc[mt][n] = (floatx4){0.f, 0.f, 0.f, 0.f};

  __syncthreads();

  #pragma unroll
  for (int mt = 0; mt < 8; ++mt) {
    #pragma unroll
    for (int ks = 0; ks < 4; ++ks) {
      int ai = ((mt * 4 + ks) * 64 + lane) * 8;
      short8 ah = *(const short8*)(sAhi + ai);
      short8 al = *(const short8*)(sAlo + ai);
      #pragma unroll
      for (int n = 0; n < 2; ++n) {
        acc[mt][n] = __builtin_amdgcn_mfma_f32_16x16x32_bf16(ah, bh[n][ks], acc[mt][n], 0, 0, 0);
        acc[mt][n] = __builtin_amdgcn_mfma_f32_16x16x32_bf16(al, bh[n][ks], acc[mt][n], 0, 0, 0);
        acc[mt][n] = __builtin_amdgcn_mfma_f32_16x16x32_bf16(ah, bl[n][ks], acc[mt][n], 0, 0, 0);
      }
    }
  }

  // epilogue: score[m] = sum_e Wr3[e]*relu(C[m][e] + c[b][e])
  float w3[2], cb[2];
  #pragma unroll
  for (int n = 0; n < 2; ++n) {
    int e = (wave * 2 + n) * 16 + col;
    w3[n] = Wr3[e];
    cb[n] = cvec[b * D_ + e];
  }
  float part[8][4];
  #pragma unroll
  for (int mt = 0; mt < 8; ++mt)
    #pragma unroll
    for (int r = 0; r < 4; ++r) {
      float s = 0.f;
      #pragma unroll
      for (int n = 0; n < 2; ++n)
        s += w3[n] * fmaxf(acc[mt][n][r] + cb[n], 0.f);
      s += __shfl_xor(s, 1, 64);
      s += __shfl_xor(s, 2, 64);
      s += __shfl_xor(s, 4, 64);
      s += __shfl_xor(s, 8, 64);
      part[mt][r] = s;
    }
  __syncthreads();              // A tile no longer needed; reuse as reduction buf
  float* red = (float*)sAhi;    // [4 waves][128 rows]
  if (col == 0) {
    #pragma unroll
    for (int mt = 0; mt < 8; ++mt)
      #pragma unroll
      for (int r = 0; r < 4; ++r)
        red[wave * 128 + mt * 16 + quad * 4 + r] = part[mt][r];
  }
  __syncthreads();
  if (t < 128) {
    float s = (red[t] + red[128 + t]) + (red[256 + t] + red[384 + t]);
    scores[(size_t)b * L_ + lt * 128 + t] = s;
  }
}

// ---------------- fused pass C+D: entmax bisection (40 iters, fp32-bit-equiv
// to 50), compact support into LDS, gather + selu + L2-normalize.
__global__ __launch_bounds__(512) void pass_cd(
    const float* __restrict__ scores, const float* __restrict__ alpha,
    const float* __restrict__ R, float* __restrict__ out) {
  const int b = blockIdx.x, t = threadIdx.x;
  const int wave = t >> 6, lane = t & 63;
  __shared__ float sred[2][8];
  __shared__ unsigned short sidx[L_];
  __shared__ float sw[L_];
  __shared__ float ppart[512];
  __shared__ int scnt;
  const float am1 = alpha[b] - 1.0f;
  const float inv = 1.0f / am1;
  const float* S = scores + (size_t)b * L_;
  float Xs[8];
  #pragma unroll
  for (int i = 0; i < 8; ++i) Xs[i] = S[i * 512 + t] * am1;
  if (t == 0) scnt = 0;

  // block max (parity buffer 0)
  float mx = Xs[0];
  #pragma unroll
  for (int i = 1; i < 8; ++i) mx = fmaxf(mx, Xs[i]);
  #pragma unroll
  for (int m = 32; m >= 1; m >>= 1) mx = fmaxf(mx, __shfl_xor(mx, m, 64));
  if (lane == 0) sred[0][wave] = mx;
  __syncthreads();
  mx = sred[0][0];
  #pragma unroll
  for (int w = 1; w < 8; ++w) mx = fmaxf(mx, sred[0][w]);

  float tau_lo = mx - 1.0f;
  float tau_hi = mx - exp2f(-12.0f * am1);  // (1/4096)^am1
  float dm = tau_hi - tau_lo;

  int pc = 1;  // parity counter (max used buffer 0)
  auto sumP = [&](float tau) -> float {
    const int par = pc & 1;
    ++pc;
    float s = 0.f;
    #pragma unroll
    for (int i = 0; i < 8; ++i) {
      float u = Xs[i] - tau;
      if (u > 0.f) s += exp2f(inv * __log2f(u));
    }
    #pragma unroll
    for (int m = 32; m >= 1; m >>= 1) s += __shfl_xor(s, m, 64);
    if (lane == 0) sred[par][wave] = s;
    __syncthreads();
    float r = sred[par][0];
    #pragma unroll
    for (int w = 1; w < 8; ++w) r += sred[par][w];
    return r;
  };

  const float f_lo = sumP(tau_lo) - 1.0f;
  float tau_m = tau_lo;
  for (int it = 0; it < 40; ++it) {
    dm *= 0.5f;
    tau_m = tau_lo + dm;
    float f_m = sumP(tau_m) - 1.0f;
    if (f_m * f_lo >= 0.f) tau_lo = tau_m;  // uniform branch
  }

  // final p, normalize, compact support into LDS
  float p[8];
  float s = 0.f;
  #pragma unroll
  for (int i = 0; i < 8; ++i) {
    float u = Xs[i] - tau_m;
    p[i] = (u > 0.f) ? exp2f(inv * __log2f(u)) : 0.f;
    s += p[i];
  }
  {
    const int par = pc & 1;
    ++pc;
    float ss = s;
    #pragma unroll
    for (int m = 32; m >= 1; m >>= 1) ss += __shfl_xor(ss, m, 64);
    if (lane == 0) sred[par][wave] = ss;
    __syncthreads();
    s = sred[par][0];
    #pragma unroll
    for (int w = 1; w < 8; ++w) s += sred[par][w];
  }
  const float rs = 1.0f / s;
  #pragma unroll
  for (int i = 0; i < 8; ++i) {
    if (p[i] > 0.f) {
      int pos = atomicAdd(&scnt, 1);
      sidx[pos] = (unsigned short)(i * 512 + t);
      sw[pos] = p[i] * rs;
    }
  }
  __syncthreads();
  const int n = scnt;

  // gather: 4 groups of 128 threads split the support list
  const float* Rb = R + (size_t)b * L_ * D_;
  const int g = t >> 7, c = t & 127;
  float acc = 0.f;
  int k = g;
  for (; k + 4 < n; k += 8) {
    int i0 = sidx[k], i1 = sidx[k + 4];
    float w0 = sw[k], w1 = sw[k + 4];
    acc += w0 * Rb[(size_t)i0 * D_ + c] + w1 * Rb[(size_t)i1 * D_ + c];
  }
  for (; k < n; k += 4) acc += sw[k] * Rb[(size_t)sidx[k] * D_ + c];
  __syncthreads();
  ppart[t] = acc;
  __syncthreads();
  float r = 0.f;
  if (t < 128) {
    float a2 = (ppart[t] + ppart[t + 128]) + (ppart[t + 256] + ppart[t + 384]);
    const float sc = 1.0507009873554805f, al = 1.6732632423543772f;
    r = a2 > 0.f ? sc * a2 : sc * al * (expf(a2) - 1.0f);
  }
  float q = r * r;
  #pragma unroll
  for (int m = 32; m >= 1; m >>= 1) q += __shfl_xor(q, m, 64);
  if (lane == 0) sred[0][wave] = q;
  __syncthreads();
  if (t < 128) {
    float nrm = sqrtf(sred[0][0] + sred[0][1]);
    out[b * D_ + t] = r / nrm;
  }
}

extern "C" void kernel_launch(void* const* d_in, const int* in_sizes, int n_in,
                              void* d_out, int out_size, void* d_ws, size_t ws_size,
                              hipStream_t stream) {
  const float* R      = (const float*)d_in[0];
  const float* alpha  = (const float*)d_in[1];
  const float* target = (const float*)d_in[2];
  const float* Wr1    = (const float*)d_in[3];
  const float* Wr2    = (const float*)d_in[4];
  const float* Wr3    = (const float*)d_in[5];
  const float* bias_r = (const float*)d_in[6];
  const float* Wf_w   = (const float*)d_in[7];
  const float* Wf_b   = (const float*)d_in[8];
  float* out = (float*)d_out;

  char* ws = (char*)d_ws;
  float* cvec          = (float*)ws;                         // 64 KB
  unsigned short* whi  = (unsigned short*)(ws + 65536);      // 32 KB
  unsigned short* wlo  = (unsigned short*)(ws + 98304);      // 32 KB
  float* scores        = (float*)(ws + 131072);              // 2 MB

  hipLaunchKernelGGL(pass_a, dim3(B_), dim3(128), 0, stream,
                     target, Wr2, bias_r, Wf_w, Wf_b, cvec);
  hipLaunchKernelGGL(wr1_split, dim3(64), dim3(256), 0, stream, Wr1, whi, wlo);
  hipLaunchKernelGGL(pass_b, dim3(B_ * 32), dim3(256), 0, stream,
                     R, whi, wlo, cvec, Wr3, scores);
  hipLaunchKernelGGL(pass_cd, dim3(B_), dim3(512), 0, stream,
                     scores, alpha, R, out);
}